// Round 1
// baseline (1581.258 us; speedup 1.0000x reference)
//
#include <hip/hip_runtime.h>

#define N_NODES 100000
#define N_EDGES 1600000
#define E_TOT   1700000
#define HID     128
#define NGRAPH  256

// ---------------------------------------------------------------- CSR build
__global__ __launch_bounds__(256) void k_hist(const int* __restrict__ ei,
                                              int* __restrict__ deg) {
  int e = blockIdx.x * 256 + threadIdx.x;
  if (e >= E_TOT) return;
  int dst = (e < N_EDGES) ? ei[N_EDGES + e] : (e - N_EDGES);
  atomicAdd(&deg[dst], 1);
}

__global__ __launch_bounds__(1024) void k_scan1(const int* __restrict__ deg,
                                                int* __restrict__ indptr,
                                                int* __restrict__ bsum) {
  __shared__ int sh[1024];
  int t = threadIdx.x;
  int i = blockIdx.x * 1024 + t;
  int v = (i < N_NODES) ? deg[i] : 0;
  sh[t] = v;
  __syncthreads();
  for (int off = 1; off < 1024; off <<= 1) {
    int x = (t >= off) ? sh[t - off] : 0;
    __syncthreads();
    sh[t] += x;
    __syncthreads();
  }
  if (i < N_NODES) indptr[i] = sh[t] - v;  // exclusive
  if (t == 1023) bsum[blockIdx.x] = sh[1023];
}

__global__ void k_scan2(const int* __restrict__ bsum, int* __restrict__ boff,
                        int* __restrict__ indptr, int nb) {
  if (threadIdx.x == 0 && blockIdx.x == 0) {
    int run = 0;
    for (int i = 0; i < nb; ++i) { boff[i] = run; run += bsum[i]; }
    indptr[N_NODES] = run;
  }
}

__global__ __launch_bounds__(1024) void k_scan3(int* __restrict__ indptr,
                                                const int* __restrict__ boff,
                                                int* __restrict__ poscur) {
  int i = blockIdx.x * 1024 + threadIdx.x;
  if (i < N_NODES) {
    int v = indptr[i] + boff[blockIdx.x];
    indptr[i] = v;
    poscur[i] = v;
  }
}

__global__ __launch_bounds__(256) void k_scatter(const int* __restrict__ ei,
                                                 int* __restrict__ poscur,
                                                 int* __restrict__ csr_src) {
  int e = blockIdx.x * 256 + threadIdx.x;
  if (e >= E_TOT) return;
  int src, dst;
  if (e < N_EDGES) { src = ei[e]; dst = ei[N_EDGES + e]; }
  else             { src = e - N_EDGES; dst = src; }
  int p = atomicAdd(&poscur[dst], 1);
  csr_src[p] = src;
}

// ------------------------------------------------- GEMM h = X @ W^T (+ a_s/a_d)
// Block: 512 threads, 64 rows x 128 cols tile. LDS: Xs transposed [k][r],
// Wt transposed [k][o], both padded so float4 reads stay 16B-aligned.
__global__ __launch_bounds__(512) void k_gemm(const float* __restrict__ X,
                                              const float* __restrict__ W,
                                              const float* __restrict__ att_s,
                                              const float* __restrict__ att_d,
                                              float* __restrict__ H,
                                              float* __restrict__ As,
                                              float* __restrict__ Ad) {
  __shared__ float Xs[128][68];   // [c][r], stride 68 -> 16B aligned rows
  __shared__ float Wt[128][132];  // [c][o], stride 132 -> 16B aligned rows
  const int t = threadIdx.x;
  const int row0 = blockIdx.x * 64;

  // stage W transposed: 16384 floats, 8 x float4 per thread
#pragma unroll
  for (int i = 0; i < 8; ++i) {
    int idx = (t + i * 512) << 2;
    int o = idx >> 7, c = idx & 127;
    float4 w = *(const float4*)&W[o * 128 + c];
    Wt[c + 0][o] = w.x; Wt[c + 1][o] = w.y;
    Wt[c + 2][o] = w.z; Wt[c + 3][o] = w.w;
  }
  // stage X tile transposed: 8192 floats, 4 x float4 per thread
#pragma unroll
  for (int i = 0; i < 4; ++i) {
    int idx = (t + i * 512) << 2;
    int r = idx >> 7, c = idx & 127;
    int row = row0 + r;
    float4 xv = (row < N_NODES) ? *(const float4*)&X[row * 128 + c]
                                : float4{0.f, 0.f, 0.f, 0.f};
    Xs[c + 0][r] = xv.x; Xs[c + 1][r] = xv.y;
    Xs[c + 2][r] = xv.z; Xs[c + 3][r] = xv.w;
  }
  __syncthreads();

  const int tx = t & 31;   // col group: cols 4*tx
  const int ty = t >> 5;   // row group: rows 4*ty
  float acc[4][4] = {{0.f}};
#pragma unroll 8
  for (int k = 0; k < 128; ++k) {
    float4 xr = *(const float4*)&Xs[k][ty << 2];
    float4 wc = *(const float4*)&Wt[k][tx << 2];
    acc[0][0] += xr.x * wc.x; acc[0][1] += xr.x * wc.y;
    acc[0][2] += xr.x * wc.z; acc[0][3] += xr.x * wc.w;
    acc[1][0] += xr.y * wc.x; acc[1][1] += xr.y * wc.y;
    acc[1][2] += xr.y * wc.z; acc[1][3] += xr.y * wc.w;
    acc[2][0] += xr.z * wc.x; acc[2][1] += xr.z * wc.y;
    acc[2][2] += xr.z * wc.z; acc[2][3] += xr.z * wc.w;
    acc[3][0] += xr.w * wc.x; acc[3][1] += xr.w * wc.y;
    acc[3][2] += xr.w * wc.z; acc[3][3] += xr.w * wc.w;
  }

  // fused epilogue: a_s / a_d partial dots + reduce over the 32 tx lanes
  float4 asv = *(const float4*)&att_s[tx << 2];
  float4 adv = *(const float4*)&att_d[tx << 2];
#pragma unroll
  for (int i = 0; i < 4; ++i) {
    float ps = acc[i][0] * asv.x + acc[i][1] * asv.y +
               acc[i][2] * asv.z + acc[i][3] * asv.w;
    float pd = acc[i][0] * adv.x + acc[i][1] * adv.y +
               acc[i][2] * adv.z + acc[i][3] * adv.w;
#pragma unroll
    for (int m = 1; m < 32; m <<= 1) {
      ps += __shfl_xor(ps, m);
      pd += __shfl_xor(pd, m);
    }
    int row = row0 + (ty << 2) + i;
    if (tx == 0 && row < N_NODES) { As[row] = ps; Ad[row] = pd; }
    if (row < N_NODES) {
      float4 hv{acc[i][0], acc[i][1], acc[i][2], acc[i][3]};
      *(float4*)&H[row * 128 + (tx << 2)] = hv;
    }
  }
}

// ------------------------------------- attention softmax + aggregation (CSR)
// one wave per dst node
__global__ __launch_bounds__(256) void k_agg(const float* __restrict__ H,
                                             const float* __restrict__ a_s,
                                             const float* __restrict__ a_d,
                                             const int* __restrict__ indptr,
                                             const int* __restrict__ csr_src,
                                             const float* __restrict__ bias,
                                             float* __restrict__ OUT) {
  int n = blockIdx.x * 4 + (threadIdx.x >> 6);
  if (n >= N_NODES) return;
  int lane = threadIdx.x & 63;
  int start = indptr[n], end = indptr[n + 1];
  float adn = a_d[n];

  // pass 1a: wave max of leaky_relu(a_s[src]+a_d[n])
  float lmax = -1e30f;
  for (int idx = start + lane; idx < end; idx += 64) {
    int s = csr_src[idx];
    float e = a_s[s] + adn;
    e = (e > 0.f) ? e : 0.2f * e;
    lmax = fmaxf(lmax, e);
  }
#pragma unroll
  for (int m = 1; m < 64; m <<= 1) lmax = fmaxf(lmax, __shfl_xor(lmax, m));

  // pass 1b: sum of exp(e - m)
  float lsum = 0.f;
  for (int idx = start + lane; idx < end; idx += 64) {
    int s = csr_src[idx];
    float e = a_s[s] + adn;
    e = (e > 0.f) ? e : 0.2f * e;
    lsum += __expf(e - lmax);
  }
#pragma unroll
  for (int m = 1; m < 64; m <<= 1) lsum += __shfl_xor(lsum, m);
  float inv = 1.0f / lsum;

  // pass 2: weighted feature aggregation, lanes over channels
  float accx = 0.f, accy = 0.f;
  for (int idx = start; idx < end; ++idx) {
    int s = csr_src[idx];
    float e = a_s[s] + adn;
    e = (e > 0.f) ? e : 0.2f * e;
    float al = __expf(e - lmax) * inv;
    float2 hv = *(const float2*)&H[s * 128 + 2 * lane];
    accx += al * hv.x;
    accy += al * hv.y;
  }
  float2 b2 = *(const float2*)&bias[2 * lane];
  float ox = accx + b2.x, oy = accy + b2.y;
  ox = fmaxf(ox, 0.f); oy = fmaxf(oy, 0.f);   // relu
  float2 ov{ox, oy};
  *(float2*)&OUT[n * 128 + 2 * lane] = ov;
}

// ---------------------------------------------- head (128->8, tanh) + pool
__global__ __launch_bounds__(256) void k_head(const float* __restrict__ H,
                                              const float* __restrict__ Wl,
                                              const float* __restrict__ bl,
                                              const int* __restrict__ batch,
                                              float* __restrict__ pool,
                                              float* __restrict__ cntf) {
  __shared__ float Wls[8][128];
  int t = threadIdx.x;
#pragma unroll
  for (int i = 0; i < 4; ++i) {
    int idx = t + i * 256;
    Wls[idx >> 7][idx & 127] = Wl[idx];
  }
  __syncthreads();

  int n = blockIdx.x * 4 + (t >> 6);
  if (n >= N_NODES) return;
  int lane = t & 63;
  float2 hv = *(const float2*)&H[n * 128 + 2 * lane];
  float va[8];
#pragma unroll
  for (int a = 0; a < 8; ++a) {
    float2 wv = *(const float2*)&Wls[a][2 * lane];
    float v = hv.x * wv.x + hv.y * wv.y;
#pragma unroll
    for (int m = 1; m < 64; m <<= 1) v += __shfl_xor(v, m);
    va[a] = v;
  }
  if (lane == 0) {
    int b = batch[n];
#pragma unroll
    for (int a = 0; a < 8; ++a)
      atomicAdd(&pool[b * 8 + a], tanhf(va[a] + bl[a]));
    atomicAdd(&cntf[b], 1.0f);
  }
}

__global__ __launch_bounds__(256) void k_final(const float* __restrict__ pool,
                                               const float* __restrict__ cntf,
                                               float* __restrict__ out) {
  int i = blockIdx.x * 256 + threadIdx.x;
  if (i < NGRAPH * 8) out[i] = pool[i] / fmaxf(cntf[i >> 3], 1.0f);
}

// ---------------------------------------------------------------- launcher
extern "C" void kernel_launch(void* const* d_in, const int* in_sizes, int n_in,
                              void* d_out, int out_size, void* d_ws, size_t ws_size,
                              hipStream_t stream) {
  const float* x   = (const float*)d_in[0];
  const int*   ei  = (const int*)d_in[1];
  const int*   bat = (const int*)d_in[2];
  const float* Wm[3]  = {(const float*)d_in[3],  (const float*)d_in[7],  (const float*)d_in[11]};
  const float* asv[3] = {(const float*)d_in[4],  (const float*)d_in[8],  (const float*)d_in[12]};
  const float* adv[3] = {(const float*)d_in[5],  (const float*)d_in[9],  (const float*)d_in[13]};
  const float* bv[3]  = {(const float*)d_in[6],  (const float*)d_in[10], (const float*)d_in[14]};
  const float* Wl  = (const float*)d_in[15];
  const float* bl  = (const float*)d_in[16];
  float* out = (float*)d_out;

  char* w = (char*)d_ws;
  float* hA    = (float*)(w + 0);          // 51,200,000 B
  float* hB    = (float*)(w + 51200000);   // 51,200,000 B
  float* a_s   = (float*)(w + 102400000);  // 400,000 B
  float* a_d   = (float*)(w + 102800000);  // 400,000 B
  int*   deg   = (int*)  (w + 103200000);  // 400,000 B
  int*   indptr= (int*)  (w + 103600000);  // 400,128 B (100001 ints)
  int*   poscur= (int*)  (w + 104000128);  // 400,000 B
  int*   bsum  = (int*)  (w + 104400128);  // 512 B
  int*   boff  = (int*)  (w + 104400640);  // 512 B
  int*   csr   = (int*)  (w + 104401152);  // 6,800,000 B
  float* pool  = (float*)(w + 111201152);  // 8192 B
  float* cntf  = (float*)(w + 111209344);  // 1024 B

  hipMemsetAsync(deg, 0, N_NODES * sizeof(int), stream);
  hipMemsetAsync(pool, 0, (NGRAPH * 8 + NGRAPH) * sizeof(float), stream);

  // CSR build (by dst), reused for all 3 layers
  k_hist   <<<(E_TOT + 255) / 256, 256, 0, stream>>>(ei, deg);
  k_scan1  <<<98, 1024, 0, stream>>>(deg, indptr, bsum);
  k_scan2  <<<1, 64, 0, stream>>>(bsum, boff, indptr, 98);
  k_scan3  <<<98, 1024, 0, stream>>>(indptr, boff, poscur);
  k_scatter<<<(E_TOT + 255) / 256, 256, 0, stream>>>(ei, poscur, csr);

  const float* in = x;
  for (int l = 0; l < 3; ++l) {
    k_gemm<<<(N_NODES + 63) / 64, 512, 0, stream>>>(in, Wm[l], asv[l], adv[l],
                                                    hA, a_s, a_d);
    k_agg <<<N_NODES / 4, 256, 0, stream>>>(hA, a_s, a_d, indptr, csr, bv[l], hB);
    in = hB;
  }

  k_head <<<N_NODES / 4, 256, 0, stream>>>(hB, Wl, bl, bat, pool, cntf);
  k_final<<<8, 256, 0, stream>>>(pool, cntf, out);
}

// Round 2
// 1163.371 us; speedup vs baseline: 1.3592x; 1.3592x over previous
//
#include <hip/hip_runtime.h>

#define N_NODES 100000
#define N_EDGES 1600000
#define E_TOT   1700000
#define HID     128
#define NGRAPH  256

// ---------------------------------------------------------------- CSR build
__global__ __launch_bounds__(256) void k_hist(const int* __restrict__ ei,
                                              int* __restrict__ deg) {
  int e = blockIdx.x * 256 + threadIdx.x;
  if (e >= E_TOT) return;
  int dst = (e < N_EDGES) ? ei[N_EDGES + e] : (e - N_EDGES);
  atomicAdd(&deg[dst], 1);
}

__global__ __launch_bounds__(1024) void k_scan1(const int* __restrict__ deg,
                                                int* __restrict__ indptr,
                                                int* __restrict__ bsum) {
  __shared__ int sh[1024];
  int t = threadIdx.x;
  int i = blockIdx.x * 1024 + t;
  int v = (i < N_NODES) ? deg[i] : 0;
  sh[t] = v;
  __syncthreads();
  for (int off = 1; off < 1024; off <<= 1) {
    int x = (t >= off) ? sh[t - off] : 0;
    __syncthreads();
    sh[t] += x;
    __syncthreads();
  }
  if (i < N_NODES) indptr[i] = sh[t] - v;  // exclusive
  if (t == 1023) bsum[blockIdx.x] = sh[1023];
}

__global__ void k_scan2(const int* __restrict__ bsum, int* __restrict__ boff,
                        int* __restrict__ indptr, int nb) {
  if (threadIdx.x == 0 && blockIdx.x == 0) {
    int run = 0;
    for (int i = 0; i < nb; ++i) { boff[i] = run; run += bsum[i]; }
    indptr[N_NODES] = run;
  }
}

__global__ __launch_bounds__(1024) void k_scan3(int* __restrict__ indptr,
                                                const int* __restrict__ boff,
                                                int* __restrict__ poscur) {
  int i = blockIdx.x * 1024 + threadIdx.x;
  if (i < N_NODES) {
    int v = indptr[i] + boff[blockIdx.x];
    indptr[i] = v;
    poscur[i] = v;
  }
}

__global__ __launch_bounds__(256) void k_scatter(const int* __restrict__ ei,
                                                 int* __restrict__ poscur,
                                                 int* __restrict__ csr_src) {
  int e = blockIdx.x * 256 + threadIdx.x;
  if (e >= E_TOT) return;
  int src, dst;
  if (e < N_EDGES) { src = ei[e]; dst = ei[N_EDGES + e]; }
  else             { src = e - N_EDGES; dst = src; }
  int p = atomicAdd(&poscur[dst], 1);
  csr_src[p] = src;
}

// ------------------------------------------------- GEMM h = X @ W^T (+ a_s/a_d)
__global__ __launch_bounds__(512) void k_gemm(const float* __restrict__ X,
                                              const float* __restrict__ W,
                                              const float* __restrict__ att_s,
                                              const float* __restrict__ att_d,
                                              float* __restrict__ H,
                                              float* __restrict__ As,
                                              float* __restrict__ Ad) {
  __shared__ float Xs[128][68];   // [c][r]
  __shared__ float Wt[128][132];  // [c][o]
  const int t = threadIdx.x;
  const int row0 = blockIdx.x * 64;

#pragma unroll
  for (int i = 0; i < 8; ++i) {
    int idx = (t + i * 512) << 2;
    int o = idx >> 7, c = idx & 127;
    float4 w = *(const float4*)&W[o * 128 + c];
    Wt[c + 0][o] = w.x; Wt[c + 1][o] = w.y;
    Wt[c + 2][o] = w.z; Wt[c + 3][o] = w.w;
  }
#pragma unroll
  for (int i = 0; i < 4; ++i) {
    int idx = (t + i * 512) << 2;
    int r = idx >> 7, c = idx & 127;
    int row = row0 + r;
    float4 xv = (row < N_NODES) ? *(const float4*)&X[row * 128 + c]
                                : float4{0.f, 0.f, 0.f, 0.f};
    Xs[c + 0][r] = xv.x; Xs[c + 1][r] = xv.y;
    Xs[c + 2][r] = xv.z; Xs[c + 3][r] = xv.w;
  }
  __syncthreads();

  const int tx = t & 31;
  const int ty = t >> 5;
  float acc[4][4] = {{0.f}};
#pragma unroll 8
  for (int k = 0; k < 128; ++k) {
    float4 xr = *(const float4*)&Xs[k][ty << 2];
    float4 wc = *(const float4*)&Wt[k][tx << 2];
    acc[0][0] += xr.x * wc.x; acc[0][1] += xr.x * wc.y;
    acc[0][2] += xr.x * wc.z; acc[0][3] += xr.x * wc.w;
    acc[1][0] += xr.y * wc.x; acc[1][1] += xr.y * wc.y;
    acc[1][2] += xr.y * wc.z; acc[1][3] += xr.y * wc.w;
    acc[2][0] += xr.z * wc.x; acc[2][1] += xr.z * wc.y;
    acc[2][2] += xr.z * wc.z; acc[2][3] += xr.z * wc.w;
    acc[3][0] += xr.w * wc.x; acc[3][1] += xr.w * wc.y;
    acc[3][2] += xr.w * wc.z; acc[3][3] += xr.w * wc.w;
  }

  float4 asv = *(const float4*)&att_s[tx << 2];
  float4 adv = *(const float4*)&att_d[tx << 2];
#pragma unroll
  for (int i = 0; i < 4; ++i) {
    float ps = acc[i][0] * asv.x + acc[i][1] * asv.y +
               acc[i][2] * asv.z + acc[i][3] * asv.w;
    float pd = acc[i][0] * adv.x + acc[i][1] * adv.y +
               acc[i][2] * adv.z + acc[i][3] * adv.w;
#pragma unroll
    for (int m = 1; m < 32; m <<= 1) {
      ps += __shfl_xor(ps, m);
      pd += __shfl_xor(pd, m);
    }
    int row = row0 + (ty << 2) + i;
    if (tx == 0 && row < N_NODES) { As[row] = ps; Ad[row] = pd; }
    if (row < N_NODES) {
      float4 hv{acc[i][0], acc[i][1], acc[i][2], acc[i][3]};
      *(float4*)&H[row * 128 + (tx << 2)] = hv;
    }
  }
}

// ------------------------------------- attention softmax + aggregation (CSR)
__global__ __launch_bounds__(256) void k_agg(const float* __restrict__ H,
                                             const float* __restrict__ a_s,
                                             const float* __restrict__ a_d,
                                             const int* __restrict__ indptr,
                                             const int* __restrict__ csr_src,
                                             const float* __restrict__ bias,
                                             float* __restrict__ OUT) {
  int n = blockIdx.x * 4 + (threadIdx.x >> 6);
  if (n >= N_NODES) return;
  int lane = threadIdx.x & 63;
  int start = indptr[n], end = indptr[n + 1];
  float adn = a_d[n];

  float lmax = -1e30f;
  for (int idx = start + lane; idx < end; idx += 64) {
    int s = csr_src[idx];
    float e = a_s[s] + adn;
    e = (e > 0.f) ? e : 0.2f * e;
    lmax = fmaxf(lmax, e);
  }
#pragma unroll
  for (int m = 1; m < 64; m <<= 1) lmax = fmaxf(lmax, __shfl_xor(lmax, m));

  float lsum = 0.f;
  for (int idx = start + lane; idx < end; idx += 64) {
    int s = csr_src[idx];
    float e = a_s[s] + adn;
    e = (e > 0.f) ? e : 0.2f * e;
    lsum += __expf(e - lmax);
  }
#pragma unroll
  for (int m = 1; m < 64; m <<= 1) lsum += __shfl_xor(lsum, m);
  float inv = 1.0f / lsum;

  float accx = 0.f, accy = 0.f;
  for (int idx = start; idx < end; ++idx) {
    int s = csr_src[idx];
    float e = a_s[s] + adn;
    e = (e > 0.f) ? e : 0.2f * e;
    float al = __expf(e - lmax) * inv;
    float2 hv = *(const float2*)&H[s * 128 + 2 * lane];
    accx += al * hv.x;
    accy += al * hv.y;
  }
  float2 b2 = *(const float2*)&bias[2 * lane];
  float ox = accx + b2.x, oy = accy + b2.y;
  ox = fmaxf(ox, 0.f); oy = fmaxf(oy, 0.f);   // relu
  float2 ov{ox, oy};
  *(float2*)&OUT[n * 128 + 2 * lane] = ov;
}

// ---------------------------------------------- head (128->8, tanh), no atomics
__global__ __launch_bounds__(256) void k_head(const float* __restrict__ H,
                                              const float* __restrict__ Wl,
                                              const float* __restrict__ bl,
                                              float* __restrict__ h8) {
  __shared__ float Wls[8][128];
  int t = threadIdx.x;
#pragma unroll
  for (int i = 0; i < 4; ++i) {
    int idx = t + i * 256;
    Wls[idx >> 7][idx & 127] = Wl[idx];
  }
  __syncthreads();

  int n = blockIdx.x * 4 + (t >> 6);
  if (n >= N_NODES) return;
  int lane = t & 63;
  float2 hv = *(const float2*)&H[n * 128 + 2 * lane];
  float mine = 0.f;
#pragma unroll
  for (int a = 0; a < 8; ++a) {
    float2 wv = *(const float2*)&Wls[a][2 * lane];
    float v = hv.x * wv.x + hv.y * wv.y;
#pragma unroll
    for (int m = 1; m < 64; m <<= 1) v += __shfl_xor(v, m);
    if (lane == a) mine = v;
  }
  if (lane < 8) h8[n * 8 + lane] = tanhf(mine + bl[lane]);
}

// ------------------------------------ mean pool: one block per graph, no atomics
__global__ __launch_bounds__(256) void k_pool(const float* __restrict__ h8,
                                              const int* __restrict__ batch,
                                              float* __restrict__ out) {
  int g = blockIdx.x;
  __shared__ int bounds[2];
  if (threadIdx.x < 2) {
    int target = g + threadIdx.x;
    int lo = 0, hi = N_NODES;
    while (lo < hi) {
      int mid = (lo + hi) >> 1;
      if (batch[mid] < target) lo = mid + 1; else hi = mid;
    }
    bounds[threadIdx.x] = lo;
  }
  __syncthreads();
  int lo = bounds[0], hi = bounds[1];
  int ch = threadIdx.x & 7;
  float acc = 0.f;
  for (int n = lo + (threadIdx.x >> 3); n < hi; n += 32)
    acc += h8[n * 8 + ch];

  __shared__ float red[256];
  red[threadIdx.x] = acc;
  __syncthreads();
  for (int off = 128; off >= 8; off >>= 1) {
    if (threadIdx.x < off) red[threadIdx.x] += red[threadIdx.x + off];
    __syncthreads();
  }
  if (threadIdx.x < 8)
    out[g * 8 + threadIdx.x] = red[threadIdx.x] / fmaxf((float)(hi - lo), 1.0f);
}

// ---------------------------------------------------------------- launcher
extern "C" void kernel_launch(void* const* d_in, const int* in_sizes, int n_in,
                              void* d_out, int out_size, void* d_ws, size_t ws_size,
                              hipStream_t stream) {
  const float* x   = (const float*)d_in[0];
  const int*   ei  = (const int*)d_in[1];
  const int*   bat = (const int*)d_in[2];
  const float* Wm[3]  = {(const float*)d_in[3],  (const float*)d_in[7],  (const float*)d_in[11]};
  const float* asv[3] = {(const float*)d_in[4],  (const float*)d_in[8],  (const float*)d_in[12]};
  const float* adv[3] = {(const float*)d_in[5],  (const float*)d_in[9],  (const float*)d_in[13]};
  const float* bv[3]  = {(const float*)d_in[6],  (const float*)d_in[10], (const float*)d_in[14]};
  const float* Wl  = (const float*)d_in[15];
  const float* bl  = (const float*)d_in[16];
  float* out = (float*)d_out;

  char* w = (char*)d_ws;
  float* hA    = (float*)(w + 0);          // 51,200,000 B
  float* hB    = (float*)(w + 51200000);   // 51,200,000 B
  float* a_s   = (float*)(w + 102400000);  // 400,000 B
  float* a_d   = (float*)(w + 102800000);  // 400,000 B
  int*   deg   = (int*)  (w + 103200000);  // 400,000 B
  int*   indptr= (int*)  (w + 103600000);  // 400,128 B
  int*   poscur= (int*)  (w + 104000128);  // 400,000 B
  int*   bsum  = (int*)  (w + 104400128);  // 512 B
  int*   boff  = (int*)  (w + 104400640);  // 512 B
  int*   csr   = (int*)  (w + 104401152);  // 6,800,000 B
  float* h8    = hA;                       // reuse: hA free after layer-3 agg

  hipMemsetAsync(deg, 0, N_NODES * sizeof(int), stream);

  k_hist   <<<(E_TOT + 255) / 256, 256, 0, stream>>>(ei, deg);
  k_scan1  <<<98, 1024, 0, stream>>>(deg, indptr, bsum);
  k_scan2  <<<1, 64, 0, stream>>>(bsum, boff, indptr, 98);
  k_scan3  <<<98, 1024, 0, stream>>>(indptr, boff, poscur);
  k_scatter<<<(E_TOT + 255) / 256, 256, 0, stream>>>(ei, poscur, csr);

  const float* in = x;
  for (int l = 0; l < 3; ++l) {
    k_gemm<<<(N_NODES + 63) / 64, 512, 0, stream>>>(in, Wm[l], asv[l], adv[l],
                                                    hA, a_s, a_d);
    k_agg <<<N_NODES / 4, 256, 0, stream>>>(hA, a_s, a_d, indptr, csr, bv[l], hB);
    in = hB;
  }

  k_head<<<N_NODES / 4, 256, 0, stream>>>(hB, Wl, bl, h8);
  k_pool<<<NGRAPH, 256, 0, stream>>>(h8, bat, out);
}

// Round 3
// 938.783 us; speedup vs baseline: 1.6844x; 1.2392x over previous
//
#include <hip/hip_runtime.h>

#define N_NODES 100000
#define N_EDGES 1600000
#define E_TOT   1700000
#define HID     128
#define NGRAPH  256

// ---------------------------------------------------------------- CSR build
__global__ __launch_bounds__(256) void k_hist(const int* __restrict__ ei,
                                              int* __restrict__ deg) {
  int e = blockIdx.x * 256 + threadIdx.x;
  if (e >= E_TOT) return;
  int dst = (e < N_EDGES) ? ei[N_EDGES + e] : (e - N_EDGES);
  atomicAdd(&deg[dst], 1);
}

__global__ __launch_bounds__(1024) void k_scan1(const int* __restrict__ deg,
                                                int* __restrict__ indptr,
                                                int* __restrict__ bsum) {
  __shared__ int sh[1024];
  int t = threadIdx.x;
  int i = blockIdx.x * 1024 + t;
  int v = (i < N_NODES) ? deg[i] : 0;
  sh[t] = v;
  __syncthreads();
  for (int off = 1; off < 1024; off <<= 1) {
    int x = (t >= off) ? sh[t - off] : 0;
    __syncthreads();
    sh[t] += x;
    __syncthreads();
  }
  if (i < N_NODES) indptr[i] = sh[t] - v;  // exclusive
  if (t == 1023) bsum[blockIdx.x] = sh[1023];
}

__global__ void k_scan2(const int* __restrict__ bsum, int* __restrict__ boff,
                        int* __restrict__ indptr, int nb) {
  if (threadIdx.x == 0 && blockIdx.x == 0) {
    int run = 0;
    for (int i = 0; i < nb; ++i) { boff[i] = run; run += bsum[i]; }
    indptr[N_NODES] = run;
  }
}

__global__ __launch_bounds__(1024) void k_scan3(int* __restrict__ indptr,
                                                const int* __restrict__ boff,
                                                int* __restrict__ poscur) {
  int i = blockIdx.x * 1024 + threadIdx.x;
  if (i < N_NODES) {
    int v = indptr[i] + boff[blockIdx.x];
    indptr[i] = v;
    poscur[i] = v;
  }
}

__global__ __launch_bounds__(256) void k_scatter(const int* __restrict__ ei,
                                                 int* __restrict__ poscur,
                                                 int* __restrict__ csr_src) {
  int e = blockIdx.x * 256 + threadIdx.x;
  if (e >= E_TOT) return;
  int src, dst;
  if (e < N_EDGES) { src = ei[e]; dst = ei[N_EDGES + e]; }
  else             { src = e - N_EDGES; dst = src; }
  int p = atomicAdd(&poscur[dst], 1);
  csr_src[p] = src;
}

// ------------------------------------------------- GEMM h = X @ W^T (+ a_s/a_d)
__global__ __launch_bounds__(512) void k_gemm(const float* __restrict__ X,
                                              const float* __restrict__ W,
                                              const float* __restrict__ att_s,
                                              const float* __restrict__ att_d,
                                              float* __restrict__ H,
                                              float* __restrict__ As,
                                              float* __restrict__ Ad) {
  __shared__ float Xs[128][68];   // [c][r]
  __shared__ float Wt[128][132];  // [c][o]
  const int t = threadIdx.x;
  const int row0 = blockIdx.x * 64;

#pragma unroll
  for (int i = 0; i < 8; ++i) {
    int idx = (t + i * 512) << 2;
    int o = idx >> 7, c = idx & 127;
    float4 w = *(const float4*)&W[o * 128 + c];
    Wt[c + 0][o] = w.x; Wt[c + 1][o] = w.y;
    Wt[c + 2][o] = w.z; Wt[c + 3][o] = w.w;
  }
#pragma unroll
  for (int i = 0; i < 4; ++i) {
    int idx = (t + i * 512) << 2;
    int r = idx >> 7, c = idx & 127;
    int row = row0 + r;
    float4 xv = (row < N_NODES) ? *(const float4*)&X[row * 128 + c]
                                : float4{0.f, 0.f, 0.f, 0.f};
    Xs[c + 0][r] = xv.x; Xs[c + 1][r] = xv.y;
    Xs[c + 2][r] = xv.z; Xs[c + 3][r] = xv.w;
  }
  __syncthreads();

  const int tx = t & 31;
  const int ty = t >> 5;
  float acc[4][4] = {{0.f}};
#pragma unroll 8
  for (int k = 0; k < 128; ++k) {
    float4 xr = *(const float4*)&Xs[k][ty << 2];
    float4 wc = *(const float4*)&Wt[k][tx << 2];
    acc[0][0] += xr.x * wc.x; acc[0][1] += xr.x * wc.y;
    acc[0][2] += xr.x * wc.z; acc[0][3] += xr.x * wc.w;
    acc[1][0] += xr.y * wc.x; acc[1][1] += xr.y * wc.y;
    acc[1][2] += xr.y * wc.z; acc[1][3] += xr.y * wc.w;
    acc[2][0] += xr.z * wc.x; acc[2][1] += xr.z * wc.y;
    acc[2][2] += xr.z * wc.z; acc[2][3] += xr.z * wc.w;
    acc[3][0] += xr.w * wc.x; acc[3][1] += xr.w * wc.y;
    acc[3][2] += xr.w * wc.z; acc[3][3] += xr.w * wc.w;
  }

  float4 asv = *(const float4*)&att_s[tx << 2];
  float4 adv = *(const float4*)&att_d[tx << 2];
#pragma unroll
  for (int i = 0; i < 4; ++i) {
    float ps = acc[i][0] * asv.x + acc[i][1] * asv.y +
               acc[i][2] * asv.z + acc[i][3] * asv.w;
    float pd = acc[i][0] * adv.x + acc[i][1] * adv.y +
               acc[i][2] * adv.z + acc[i][3] * adv.w;
#pragma unroll
    for (int m = 1; m < 32; m <<= 1) {
      ps += __shfl_xor(ps, m);
      pd += __shfl_xor(pd, m);
    }
    int row = row0 + (ty << 2) + i;
    if (tx == 0 && row < N_NODES) { As[row] = ps; Ad[row] = pd; }
    if (row < N_NODES) {
      float4 hv{acc[i][0], acc[i][1], acc[i][2], acc[i][3]};
      *(float4*)&H[row * 128 + (tx << 2)] = hv;
    }
  }
}

// ------------------------------------- attention softmax + aggregation (CSR)
// one wave per dst node; aggregation: 2 edges per step (half-waves), float4
// per lane, 4-deep unrolled main loop for memory-level parallelism.
__global__ __launch_bounds__(256) void k_agg(const float* __restrict__ H,
                                             const float* __restrict__ a_s,
                                             const float* __restrict__ a_d,
                                             const int* __restrict__ indptr,
                                             const int* __restrict__ csr_src,
                                             const float* __restrict__ bias,
                                             float* __restrict__ OUT) {
  int n = blockIdx.x * 4 + (threadIdx.x >> 6);
  if (n >= N_NODES) return;
  const int lane = threadIdx.x & 63;
  const int start = indptr[n];
  const int deg = indptr[n + 1] - start;   // >= 1 (self-loop)
  const float adn = a_d[n];

  // ---- softmax stats; lane caches its first edge in registers ----
  int   s0 = csr_src[start + ((lane < deg) ? lane : 0)];
  float e0 = -1e30f;
  if (lane < deg) {
    float e = a_s[s0] + adn;
    e0 = (e > 0.f) ? e : 0.2f * e;
  }
  float lmax = e0;
  for (int j = lane + 64; j < deg; j += 64) {
    float e = a_s[csr_src[start + j]] + adn;
    e = (e > 0.f) ? e : 0.2f * e;
    lmax = fmaxf(lmax, e);
  }
#pragma unroll
  for (int m = 1; m < 64; m <<= 1) lmax = fmaxf(lmax, __shfl_xor(lmax, m));

  float ex0 = (lane < deg) ? __expf(e0 - lmax) : 0.f;
  float lsum = ex0;
  for (int j = lane + 64; j < deg; j += 64) {
    float e = a_s[csr_src[start + j]] + adn;
    e = (e > 0.f) ? e : 0.2f * e;
    lsum += __expf(e - lmax);
  }
#pragma unroll
  for (int m = 1; m < 64; m <<= 1) lsum += __shfl_xor(lsum, m);
  const float inv = 1.0f / lsum;

  // ---- aggregation ----
  const int half = lane >> 5;           // 0: even edges, 1: odd edges
  const int ch4 = (lane & 31) << 2;     // my 4 channels
  float4 acc = {0.f, 0.f, 0.f, 0.f};

  for (int base = 0; base < deg; base += 64) {
    float myal;
    int mys;
    if (base == 0) {
      myal = ex0 * inv;                 // 0 for lane >= deg
      mys = s0;
    } else {                            // deg > 64: essentially never, but correct
      int j = base + lane;
      mys = csr_src[start + ((j < deg) ? j : 0)];
      myal = 0.f;
      if (j < deg) {
        float e = a_s[mys] + adn;
        e = (e > 0.f) ? e : 0.2f * e;
        myal = __expf(e - lmax) * inv;
      }
    }
    const int cnt = min(deg - base, 64);
    const int np = (cnt + 1) >> 1;      // pairs this chunk
    int p0 = 0;
    for (; p0 + 4 <= np; p0 += 4) {
      float av[4]; int sv[4]; float4 hv[4];
#pragma unroll
      for (int u = 0; u < 4; ++u) {
        int j2 = 2 * (p0 + u) + half;   // <= 2*np-1 <= 63
        av[u] = __shfl(myal, j2);       // 0 when j2 >= cnt
        sv[u] = __shfl(mys, j2);        // valid row either way
      }
#pragma unroll
      for (int u = 0; u < 4; ++u)
        hv[u] = *(const float4*)&H[sv[u] * 128 + ch4];
#pragma unroll
      for (int u = 0; u < 4; ++u) {
        acc.x += av[u] * hv[u].x; acc.y += av[u] * hv[u].y;
        acc.z += av[u] * hv[u].z; acc.w += av[u] * hv[u].w;
      }
    }
    for (; p0 < np; ++p0) {
      int j2 = 2 * p0 + half;
      float a = __shfl(myal, j2);
      int s = __shfl(mys, j2);
      float4 hv = *(const float4*)&H[s * 128 + ch4];
      acc.x += a * hv.x; acc.y += a * hv.y;
      acc.z += a * hv.z; acc.w += a * hv.w;
    }
  }

  // combine even/odd halves, bias + relu, write
  acc.x += __shfl_xor(acc.x, 32);
  acc.y += __shfl_xor(acc.y, 32);
  acc.z += __shfl_xor(acc.z, 32);
  acc.w += __shfl_xor(acc.w, 32);
  if (half == 0) {
    float4 bv = *(const float4*)&bias[ch4];
    float4 o;
    o.x = fmaxf(acc.x + bv.x, 0.f);
    o.y = fmaxf(acc.y + bv.y, 0.f);
    o.z = fmaxf(acc.z + bv.z, 0.f);
    o.w = fmaxf(acc.w + bv.w, 0.f);
    *(float4*)&OUT[n * 128 + ch4] = o;
  }
}

// ---------------------------------------------- head (128->8, tanh), no atomics
__global__ __launch_bounds__(256) void k_head(const float* __restrict__ H,
                                              const float* __restrict__ Wl,
                                              const float* __restrict__ bl,
                                              float* __restrict__ h8) {
  __shared__ float Wls[8][128];
  int t = threadIdx.x;
#pragma unroll
  for (int i = 0; i < 4; ++i) {
    int idx = t + i * 256;
    Wls[idx >> 7][idx & 127] = Wl[idx];
  }
  __syncthreads();

  int n = blockIdx.x * 4 + (t >> 6);
  if (n >= N_NODES) return;
  int lane = t & 63;
  float2 hv = *(const float2*)&H[n * 128 + 2 * lane];
  float mine = 0.f;
#pragma unroll
  for (int a = 0; a < 8; ++a) {
    float2 wv = *(const float2*)&Wls[a][2 * lane];
    float v = hv.x * wv.x + hv.y * wv.y;
#pragma unroll
    for (int m = 1; m < 64; m <<= 1) v += __shfl_xor(v, m);
    if (lane == a) mine = v;
  }
  if (lane < 8) h8[n * 8 + lane] = tanhf(mine + bl[lane]);
}

// ------------------------------------ mean pool: one block per graph, no atomics
__global__ __launch_bounds__(256) void k_pool(const float* __restrict__ h8,
                                              const int* __restrict__ batch,
                                              float* __restrict__ out) {
  int g = blockIdx.x;
  __shared__ int bounds[2];
  if (threadIdx.x < 2) {
    int target = g + threadIdx.x;
    int lo = 0, hi = N_NODES;
    while (lo < hi) {
      int mid = (lo + hi) >> 1;
      if (batch[mid] < target) lo = mid + 1; else hi = mid;
    }
    bounds[threadIdx.x] = lo;
  }
  __syncthreads();
  int lo = bounds[0], hi = bounds[1];
  int ch = threadIdx.x & 7;
  float acc = 0.f;
  for (int n = lo + (threadIdx.x >> 3); n < hi; n += 32)
    acc += h8[n * 8 + ch];

  __shared__ float red[256];
  red[threadIdx.x] = acc;
  __syncthreads();
  for (int off = 128; off >= 8; off >>= 1) {
    if (threadIdx.x < off) red[threadIdx.x] += red[threadIdx.x + off];
    __syncthreads();
  }
  if (threadIdx.x < 8)
    out[g * 8 + threadIdx.x] = red[threadIdx.x] / fmaxf((float)(hi - lo), 1.0f);
}

// ---------------------------------------------------------------- launcher
extern "C" void kernel_launch(void* const* d_in, const int* in_sizes, int n_in,
                              void* d_out, int out_size, void* d_ws, size_t ws_size,
                              hipStream_t stream) {
  const float* x   = (const float*)d_in[0];
  const int*   ei  = (const int*)d_in[1];
  const int*   bat = (const int*)d_in[2];
  const float* Wm[3]  = {(const float*)d_in[3],  (const float*)d_in[7],  (const float*)d_in[11]};
  const float* asv[3] = {(const float*)d_in[4],  (const float*)d_in[8],  (const float*)d_in[12]};
  const float* adv[3] = {(const float*)d_in[5],  (const float*)d_in[9],  (const float*)d_in[13]};
  const float* bv[3]  = {(const float*)d_in[6],  (const float*)d_in[10], (const float*)d_in[14]};
  const float* Wl  = (const float*)d_in[15];
  const float* bl  = (const float*)d_in[16];
  float* out = (float*)d_out;

  char* w = (char*)d_ws;
  float* hA    = (float*)(w + 0);          // 51,200,000 B
  float* hB    = (float*)(w + 51200000);   // 51,200,000 B
  float* a_s   = (float*)(w + 102400000);  // 400,000 B
  float* a_d   = (float*)(w + 102800000);  // 400,000 B
  int*   deg   = (int*)  (w + 103200000);  // 400,000 B
  int*   indptr= (int*)  (w + 103600000);  // 400,128 B
  int*   poscur= (int*)  (w + 104000128);  // 400,000 B
  int*   bsum  = (int*)  (w + 104400128);  // 512 B
  int*   boff  = (int*)  (w + 104400640);  // 512 B
  int*   csr   = (int*)  (w + 104401152);  // 6,800,000 B
  float* h8    = hA;                       // reuse: hA free after layer-3 agg

  hipMemsetAsync(deg, 0, N_NODES * sizeof(int), stream);

  k_hist   <<<(E_TOT + 255) / 256, 256, 0, stream>>>(ei, deg);
  k_scan1  <<<98, 1024, 0, stream>>>(deg, indptr, bsum);
  k_scan2  <<<1, 64, 0, stream>>>(bsum, boff, indptr, 98);
  k_scan3  <<<98, 1024, 0, stream>>>(indptr, boff, poscur);
  k_scatter<<<(E_TOT + 255) / 256, 256, 0, stream>>>(ei, poscur, csr);

  const float* in = x;
  for (int l = 0; l < 3; ++l) {
    k_gemm<<<(N_NODES + 63) / 64, 512, 0, stream>>>(in, Wm[l], asv[l], adv[l],
                                                    hA, a_s, a_d);
    k_agg <<<N_NODES / 4, 256, 0, stream>>>(hA, a_s, a_d, indptr, csr, bv[l], hB);
    in = hB;
  }

  k_head<<<N_NODES / 4, 256, 0, stream>>>(hB, Wl, bl, h8);
  k_pool<<<NGRAPH, 256, 0, stream>>>(h8, bat, out);
}

// Round 4
// 902.181 us; speedup vs baseline: 1.7527x; 1.0406x over previous
//
#include <hip/hip_runtime.h>

#define N_NODES 100000
#define N_EDGES 1600000
#define E_TOT   1700000
#define HID     128
#define NGRAPH  256

// ---------------------------------------------------------------- CSR build
// 8 edges per thread: independent atomic chains amortize device-atomic latency
__global__ __launch_bounds__(256) void k_hist(const int* __restrict__ ei,
                                              int* __restrict__ deg) {
  const int nth = gridDim.x * 256;
  const int tid = blockIdx.x * 256 + threadIdx.x;
  int d[8];
#pragma unroll
  for (int u = 0; u < 8; ++u) {
    int e = tid + u * nth;
    d[u] = (e < E_TOT) ? ((e < N_EDGES) ? ei[N_EDGES + e] : (e - N_EDGES)) : -1;
  }
#pragma unroll
  for (int u = 0; u < 8; ++u)
    if (d[u] >= 0) atomicAdd(&deg[d[u]], 1);
}

__global__ __launch_bounds__(1024) void k_scan1(const int* __restrict__ deg,
                                                int* __restrict__ indptr,
                                                int* __restrict__ bsum) {
  __shared__ int sh[1024];
  int t = threadIdx.x;
  int i = blockIdx.x * 1024 + t;
  int v = (i < N_NODES) ? deg[i] : 0;
  sh[t] = v;
  __syncthreads();
  for (int off = 1; off < 1024; off <<= 1) {
    int x = (t >= off) ? sh[t - off] : 0;
    __syncthreads();
    sh[t] += x;
    __syncthreads();
  }
  if (i < N_NODES) indptr[i] = sh[t] - v;  // exclusive
  if (t == 1023) bsum[blockIdx.x] = sh[1023];
}

__global__ void k_scan2(const int* __restrict__ bsum, int* __restrict__ boff,
                        int* __restrict__ indptr, int nb) {
  if (threadIdx.x == 0 && blockIdx.x == 0) {
    int run = 0;
    for (int i = 0; i < nb; ++i) { boff[i] = run; run += bsum[i]; }
    indptr[N_NODES] = run;
  }
}

__global__ __launch_bounds__(1024) void k_scan3(int* __restrict__ indptr,
                                                const int* __restrict__ boff,
                                                int* __restrict__ poscur) {
  int i = blockIdx.x * 1024 + threadIdx.x;
  if (i < N_NODES) {
    int v = indptr[i] + boff[blockIdx.x];
    indptr[i] = v;
    poscur[i] = v;
  }
}

__global__ __launch_bounds__(256) void k_scatter(const int* __restrict__ ei,
                                                 int* __restrict__ poscur,
                                                 int* __restrict__ csr_src) {
  const int nth = gridDim.x * 256;
  const int tid = blockIdx.x * 256 + threadIdx.x;
  int src[8], dst[8];
#pragma unroll
  for (int u = 0; u < 8; ++u) {
    int e = tid + u * nth;
    if (e < E_TOT) {
      if (e < N_EDGES) { src[u] = ei[e]; dst[u] = ei[N_EDGES + e]; }
      else             { src[u] = e - N_EDGES; dst[u] = src[u]; }
    } else { src[u] = -1; dst[u] = 0; }
  }
  int p[8];
#pragma unroll
  for (int u = 0; u < 8; ++u)
    if (src[u] >= 0) p[u] = atomicAdd(&poscur[dst[u]], 1);
#pragma unroll
  for (int u = 0; u < 8; ++u)
    if (src[u] >= 0) csr_src[p[u]] = src[u];
}

// ------------------------------------------------- GEMM h = X @ W^T (+ a_s/a_d)
__global__ __launch_bounds__(512) void k_gemm(const float* __restrict__ X,
                                              const float* __restrict__ W,
                                              const float* __restrict__ att_s,
                                              const float* __restrict__ att_d,
                                              float* __restrict__ H,
                                              float* __restrict__ As,
                                              float* __restrict__ Ad) {
  __shared__ float Xs[128][68];   // [c][r]
  __shared__ float Wt[128][132];  // [c][o]
  const int t = threadIdx.x;
  const int row0 = blockIdx.x * 64;

#pragma unroll
  for (int i = 0; i < 8; ++i) {
    int idx = (t + i * 512) << 2;
    int o = idx >> 7, c = idx & 127;
    float4 w = *(const float4*)&W[o * 128 + c];
    Wt[c + 0][o] = w.x; Wt[c + 1][o] = w.y;
    Wt[c + 2][o] = w.z; Wt[c + 3][o] = w.w;
  }
#pragma unroll
  for (int i = 0; i < 4; ++i) {
    int idx = (t + i * 512) << 2;
    int r = idx >> 7, c = idx & 127;
    int row = row0 + r;
    float4 xv = (row < N_NODES) ? *(const float4*)&X[row * 128 + c]
                                : float4{0.f, 0.f, 0.f, 0.f};
    Xs[c + 0][r] = xv.x; Xs[c + 1][r] = xv.y;
    Xs[c + 2][r] = xv.z; Xs[c + 3][r] = xv.w;
  }
  __syncthreads();

  const int tx = t & 31;
  const int ty = t >> 5;
  float acc[4][4] = {{0.f}};
#pragma unroll 8
  for (int k = 0; k < 128; ++k) {
    float4 xr = *(const float4*)&Xs[k][ty << 2];
    float4 wc = *(const float4*)&Wt[k][tx << 2];
    acc[0][0] += xr.x * wc.x; acc[0][1] += xr.x * wc.y;
    acc[0][2] += xr.x * wc.z; acc[0][3] += xr.x * wc.w;
    acc[1][0] += xr.y * wc.x; acc[1][1] += xr.y * wc.y;
    acc[1][2] += xr.y * wc.z; acc[1][3] += xr.y * wc.w;
    acc[2][0] += xr.z * wc.x; acc[2][1] += xr.z * wc.y;
    acc[2][2] += xr.z * wc.z; acc[2][3] += xr.z * wc.w;
    acc[3][0] += xr.w * wc.x; acc[3][1] += xr.w * wc.y;
    acc[3][2] += xr.w * wc.z; acc[3][3] += xr.w * wc.w;
  }

  float4 asv = *(const float4*)&att_s[tx << 2];
  float4 adv = *(const float4*)&att_d[tx << 2];
#pragma unroll
  for (int i = 0; i < 4; ++i) {
    float ps = acc[i][0] * asv.x + acc[i][1] * asv.y +
               acc[i][2] * asv.z + acc[i][3] * asv.w;
    float pd = acc[i][0] * adv.x + acc[i][1] * adv.y +
               acc[i][2] * adv.z + acc[i][3] * adv.w;
#pragma unroll
    for (int m = 1; m < 32; m <<= 1) {
      ps += __shfl_xor(ps, m);
      pd += __shfl_xor(pd, m);
    }
    int row = row0 + (ty << 2) + i;
    if (tx == 0 && row < N_NODES) { As[row] = ps; Ad[row] = pd; }
    if (row < N_NODES) {
      float4 hv{acc[i][0], acc[i][1], acc[i][2], acc[i][3]};
      *(float4*)&H[row * 128 + (tx << 2)] = hv;
    }
  }
}

// ------------------------------------- attention softmax + aggregation (CSR)
__global__ __launch_bounds__(256) void k_agg(const float* __restrict__ H,
                                             const float* __restrict__ a_s,
                                             const float* __restrict__ a_d,
                                             const int* __restrict__ indptr,
                                             const int* __restrict__ csr_src,
                                             const float* __restrict__ bias,
                                             float* __restrict__ OUT) {
  int n = blockIdx.x * 4 + (threadIdx.x >> 6);
  if (n >= N_NODES) return;
  const int lane = threadIdx.x & 63;
  const int start = indptr[n];
  const int deg = indptr[n + 1] - start;   // >= 1 (self-loop)
  const float adn = a_d[n];

  int   s0 = csr_src[start + ((lane < deg) ? lane : 0)];
  float e0 = -1e30f;
  if (lane < deg) {
    float e = a_s[s0] + adn;
    e0 = (e > 0.f) ? e : 0.2f * e;
  }
  float lmax = e0;
  for (int j = lane + 64; j < deg; j += 64) {
    float e = a_s[csr_src[start + j]] + adn;
    e = (e > 0.f) ? e : 0.2f * e;
    lmax = fmaxf(lmax, e);
  }
#pragma unroll
  for (int m = 1; m < 64; m <<= 1) lmax = fmaxf(lmax, __shfl_xor(lmax, m));

  float ex0 = (lane < deg) ? __expf(e0 - lmax) : 0.f;
  float lsum = ex0;
  for (int j = lane + 64; j < deg; j += 64) {
    float e = a_s[csr_src[start + j]] + adn;
    e = (e > 0.f) ? e : 0.2f * e;
    lsum += __expf(e - lmax);
  }
#pragma unroll
  for (int m = 1; m < 64; m <<= 1) lsum += __shfl_xor(lsum, m);
  const float inv = 1.0f / lsum;

  const int half = lane >> 5;           // 0: even edges, 1: odd edges
  const int ch4 = (lane & 31) << 2;     // my 4 channels
  float4 acc = {0.f, 0.f, 0.f, 0.f};

  for (int base = 0; base < deg; base += 64) {
    float myal;
    int mys;
    if (base == 0) {
      myal = ex0 * inv;
      mys = s0;
    } else {
      int j = base + lane;
      mys = csr_src[start + ((j < deg) ? j : 0)];
      myal = 0.f;
      if (j < deg) {
        float e = a_s[mys] + adn;
        e = (e > 0.f) ? e : 0.2f * e;
        myal = __expf(e - lmax) * inv;
      }
    }
    const int cnt = min(deg - base, 64);
    const int np = (cnt + 1) >> 1;
    int p0 = 0;
    for (; p0 + 4 <= np; p0 += 4) {
      float av[4]; int sv[4]; float4 hv[4];
#pragma unroll
      for (int u = 0; u < 4; ++u) {
        int j2 = 2 * (p0 + u) + half;
        av[u] = __shfl(myal, j2);
        sv[u] = __shfl(mys, j2);
      }
#pragma unroll
      for (int u = 0; u < 4; ++u)
        hv[u] = *(const float4*)&H[sv[u] * 128 + ch4];
#pragma unroll
      for (int u = 0; u < 4; ++u) {
        acc.x += av[u] * hv[u].x; acc.y += av[u] * hv[u].y;
        acc.z += av[u] * hv[u].z; acc.w += av[u] * hv[u].w;
      }
    }
    for (; p0 < np; ++p0) {
      int j2 = 2 * p0 + half;
      float a = __shfl(myal, j2);
      int s = __shfl(mys, j2);
      float4 hv = *(const float4*)&H[s * 128 + ch4];
      acc.x += a * hv.x; acc.y += a * hv.y;
      acc.z += a * hv.z; acc.w += a * hv.w;
    }
  }

  acc.x += __shfl_xor(acc.x, 32);
  acc.y += __shfl_xor(acc.y, 32);
  acc.z += __shfl_xor(acc.z, 32);
  acc.w += __shfl_xor(acc.w, 32);
  if (half == 0) {
    float4 bv = *(const float4*)&bias[ch4];
    float4 o;
    o.x = fmaxf(acc.x + bv.x, 0.f);
    o.y = fmaxf(acc.y + bv.y, 0.f);
    o.z = fmaxf(acc.z + bv.z, 0.f);
    o.w = fmaxf(acc.w + bv.w, 0.f);
    *(float4*)&OUT[n * 128 + ch4] = o;
  }
}

// ---------------------------------------------- head (128->8, tanh), no atomics
__global__ __launch_bounds__(256) void k_head(const float* __restrict__ H,
                                              const float* __restrict__ Wl,
                                              const float* __restrict__ bl,
                                              float* __restrict__ h8) {
  __shared__ float Wls[8][128];
  int t = threadIdx.x;
#pragma unroll
  for (int i = 0; i < 4; ++i) {
    int idx = t + i * 256;
    Wls[idx >> 7][idx & 127] = Wl[idx];
  }
  __syncthreads();

  int n = blockIdx.x * 4 + (t >> 6);
  if (n >= N_NODES) return;
  int lane = t & 63;
  float2 hv = *(const float2*)&H[n * 128 + 2 * lane];
  float mine = 0.f;
#pragma unroll
  for (int a = 0; a < 8; ++a) {
    float2 wv = *(const float2*)&Wls[a][2 * lane];
    float v = hv.x * wv.x + hv.y * wv.y;
#pragma unroll
    for (int m = 1; m < 64; m <<= 1) v += __shfl_xor(v, m);
    if (lane == a) mine = v;
  }
  if (lane < 8) h8[n * 8 + lane] = tanhf(mine + bl[lane]);
}

// ------------------------------------ mean pool: one block per graph, no atomics
__global__ __launch_bounds__(256) void k_pool(const float* __restrict__ h8,
                                              const int* __restrict__ batch,
                                              float* __restrict__ out) {
  int g = blockIdx.x;
  __shared__ int bounds[2];
  if (threadIdx.x < 2) {
    int target = g + threadIdx.x;
    int lo = 0, hi = N_NODES;
    while (lo < hi) {
      int mid = (lo + hi) >> 1;
      if (batch[mid] < target) lo = mid + 1; else hi = mid;
    }
    bounds[threadIdx.x] = lo;
  }
  __syncthreads();
  int lo = bounds[0], hi = bounds[1];
  int ch = threadIdx.x & 7;
  float acc = 0.f;
  for (int n = lo + (threadIdx.x >> 3); n < hi; n += 32)
    acc += h8[n * 8 + ch];

  __shared__ float red[256];
  red[threadIdx.x] = acc;
  __syncthreads();
  for (int off = 128; off >= 8; off >>= 1) {
    if (threadIdx.x < off) red[threadIdx.x] += red[threadIdx.x + off];
    __syncthreads();
  }
  if (threadIdx.x < 8)
    out[g * 8 + threadIdx.x] = red[threadIdx.x] / fmaxf((float)(hi - lo), 1.0f);
}

// ---------------------------------------------------------------- launcher
extern "C" void kernel_launch(void* const* d_in, const int* in_sizes, int n_in,
                              void* d_out, int out_size, void* d_ws, size_t ws_size,
                              hipStream_t stream) {
  const float* x   = (const float*)d_in[0];
  const int*   ei  = (const int*)d_in[1];
  const int*   bat = (const int*)d_in[2];
  const float* Wm[3]  = {(const float*)d_in[3],  (const float*)d_in[7],  (const float*)d_in[11]};
  const float* asv[3] = {(const float*)d_in[4],  (const float*)d_in[8],  (const float*)d_in[12]};
  const float* adv[3] = {(const float*)d_in[5],  (const float*)d_in[9],  (const float*)d_in[13]};
  const float* bv[3]  = {(const float*)d_in[6],  (const float*)d_in[10], (const float*)d_in[14]};
  const float* Wl  = (const float*)d_in[15];
  const float* bl  = (const float*)d_in[16];
  float* out = (float*)d_out;

  char* w = (char*)d_ws;
  float* hA    = (float*)(w + 0);          // 51,200,000 B
  float* hB    = (float*)(w + 51200000);   // 51,200,000 B
  float* a_s   = (float*)(w + 102400000);  // 400,000 B
  float* a_d   = (float*)(w + 102800000);  // 400,000 B
  int*   deg   = (int*)  (w + 103200000);  // 400,000 B
  int*   indptr= (int*)  (w + 103600000);  // 400,128 B
  int*   poscur= (int*)  (w + 104000128);  // 400,000 B
  int*   bsum  = (int*)  (w + 104400128);  // 512 B
  int*   boff  = (int*)  (w + 104400640);  // 512 B
  int*   csr   = (int*)  (w + 104401152);  // 6,800,000 B
  float* h8    = hA;                       // reuse: hA free after layer-3 agg

  hipMemsetAsync(deg, 0, N_NODES * sizeof(int), stream);

  k_hist   <<<831, 256, 0, stream>>>(ei, deg);
  k_scan1  <<<98, 1024, 0, stream>>>(deg, indptr, bsum);
  k_scan2  <<<1, 64, 0, stream>>>(bsum, boff, indptr, 98);
  k_scan3  <<<98, 1024, 0, stream>>>(indptr, boff, poscur);
  k_scatter<<<831, 256, 0, stream>>>(ei, poscur, csr);

  const float* in = x;
  for (int l = 0; l < 3; ++l) {
    k_gemm<<<(N_NODES + 63) / 64, 512, 0, stream>>>(in, Wm[l], asv[l], adv[l],
                                                    hA, a_s, a_d);
    k_agg <<<N_NODES / 4, 256, 0, stream>>>(hA, a_s, a_d, indptr, csr, bv[l], hB);
    in = hB;
  }

  k_head<<<N_NODES / 4, 256, 0, stream>>>(hB, Wl, bl, h8);
  k_pool<<<NGRAPH, 256, 0, stream>>>(h8, bat, out);
}

// Round 5
// 770.034 us; speedup vs baseline: 2.0535x; 1.1716x over previous
//
#include <hip/hip_runtime.h>

#define N_NODES 100000
#define N_EDGES 1600000
#define E_TOT   1700000
#define HID     128
#define NGRAPH  256

typedef unsigned short ushort_t;
typedef unsigned int uint_t;

__device__ inline ushort_t f2bf(float f) {   // RNE pack
  uint_t u = __float_as_uint(f);
  return (ushort_t)((u + 0x7FFFu + ((u >> 16) & 1u)) >> 16);
}

// ---------------------------------------------------------------- CSR build
__global__ __launch_bounds__(256) void k_hist(const int* __restrict__ ei,
                                              int* __restrict__ deg) {
  const int nth = gridDim.x * 256;
  const int tid = blockIdx.x * 256 + threadIdx.x;
  int d[8];
#pragma unroll
  for (int u = 0; u < 8; ++u) {
    int e = tid + u * nth;
    d[u] = (e < E_TOT) ? ((e < N_EDGES) ? ei[N_EDGES + e] : (e - N_EDGES)) : -1;
  }
#pragma unroll
  for (int u = 0; u < 8; ++u)
    if (d[u] >= 0) atomicAdd(&deg[d[u]], 1);
}

__global__ __launch_bounds__(1024) void k_scan1(const int* __restrict__ deg,
                                                int* __restrict__ indptr,
                                                int* __restrict__ bsum) {
  __shared__ int sh[1024];
  int t = threadIdx.x;
  int i = blockIdx.x * 1024 + t;
  int v = (i < N_NODES) ? deg[i] : 0;
  sh[t] = v;
  __syncthreads();
  for (int off = 1; off < 1024; off <<= 1) {
    int x = (t >= off) ? sh[t - off] : 0;
    __syncthreads();
    sh[t] += x;
    __syncthreads();
  }
  if (i < N_NODES) indptr[i] = sh[t] - v;  // exclusive
  if (t == 1023) bsum[blockIdx.x] = sh[1023];
}

__global__ void k_scan2(const int* __restrict__ bsum, int* __restrict__ boff,
                        int* __restrict__ indptr, int nb) {
  if (threadIdx.x == 0 && blockIdx.x == 0) {
    int run = 0;
    for (int i = 0; i < nb; ++i) { boff[i] = run; run += bsum[i]; }
    indptr[N_NODES] = run;
  }
}

__global__ __launch_bounds__(1024) void k_scan3(int* __restrict__ indptr,
                                                const int* __restrict__ boff,
                                                int* __restrict__ poscur) {
  int i = blockIdx.x * 1024 + threadIdx.x;
  if (i < N_NODES) {
    int v = indptr[i] + boff[blockIdx.x];
    indptr[i] = v;
    poscur[i] = v;
  }
}

__global__ __launch_bounds__(256) void k_scatter(const int* __restrict__ ei,
                                                 int* __restrict__ poscur,
                                                 int* __restrict__ csr_src) {
  const int nth = gridDim.x * 256;
  const int tid = blockIdx.x * 256 + threadIdx.x;
  int src[8], dst[8];
#pragma unroll
  for (int u = 0; u < 8; ++u) {
    int e = tid + u * nth;
    if (e < E_TOT) {
      if (e < N_EDGES) { src[u] = ei[e]; dst[u] = ei[N_EDGES + e]; }
      else             { src[u] = e - N_EDGES; dst[u] = src[u]; }
    } else { src[u] = -1; dst[u] = 0; }
  }
  int p[8];
#pragma unroll
  for (int u = 0; u < 8; ++u)
    if (src[u] >= 0) p[u] = atomicAdd(&poscur[dst[u]], 1);
#pragma unroll
  for (int u = 0; u < 8; ++u)
    if (src[u] >= 0) csr_src[p[u]] = src[u];
}

// ----------------------------------- GEMM h = X @ W^T (+ a_s/a_d), H -> bf16
__global__ __launch_bounds__(512) void k_gemm(const float* __restrict__ X,
                                              const float* __restrict__ W,
                                              const float* __restrict__ att_s,
                                              const float* __restrict__ att_d,
                                              ushort_t* __restrict__ Hb,
                                              float* __restrict__ As,
                                              float* __restrict__ Ad) {
  __shared__ float Xs[128][68];   // [c][r]
  __shared__ float Wt[128][132];  // [c][o]
  const int t = threadIdx.x;
  const int row0 = blockIdx.x * 64;

#pragma unroll
  for (int i = 0; i < 8; ++i) {
    int idx = (t + i * 512) << 2;
    int o = idx >> 7, c = idx & 127;
    float4 w = *(const float4*)&W[o * 128 + c];
    Wt[c + 0][o] = w.x; Wt[c + 1][o] = w.y;
    Wt[c + 2][o] = w.z; Wt[c + 3][o] = w.w;
  }
#pragma unroll
  for (int i = 0; i < 4; ++i) {
    int idx = (t + i * 512) << 2;
    int r = idx >> 7, c = idx & 127;
    int row = row0 + r;
    float4 xv = (row < N_NODES) ? *(const float4*)&X[row * 128 + c]
                                : float4{0.f, 0.f, 0.f, 0.f};
    Xs[c + 0][r] = xv.x; Xs[c + 1][r] = xv.y;
    Xs[c + 2][r] = xv.z; Xs[c + 3][r] = xv.w;
  }
  __syncthreads();

  const int tx = t & 31;
  const int ty = t >> 5;
  float acc[4][4] = {{0.f}};
#pragma unroll 8
  for (int k = 0; k < 128; ++k) {
    float4 xr = *(const float4*)&Xs[k][ty << 2];
    float4 wc = *(const float4*)&Wt[k][tx << 2];
    acc[0][0] += xr.x * wc.x; acc[0][1] += xr.x * wc.y;
    acc[0][2] += xr.x * wc.z; acc[0][3] += xr.x * wc.w;
    acc[1][0] += xr.y * wc.x; acc[1][1] += xr.y * wc.y;
    acc[1][2] += xr.y * wc.z; acc[1][3] += xr.y * wc.w;
    acc[2][0] += xr.z * wc.x; acc[2][1] += xr.z * wc.y;
    acc[2][2] += xr.z * wc.z; acc[2][3] += xr.z * wc.w;
    acc[3][0] += xr.w * wc.x; acc[3][1] += xr.w * wc.y;
    acc[3][2] += xr.w * wc.z; acc[3][3] += xr.w * wc.w;
  }

  float4 asv = *(const float4*)&att_s[tx << 2];
  float4 adv = *(const float4*)&att_d[tx << 2];
#pragma unroll
  for (int i = 0; i < 4; ++i) {
    float ps = acc[i][0] * asv.x + acc[i][1] * asv.y +
               acc[i][2] * asv.z + acc[i][3] * asv.w;
    float pd = acc[i][0] * adv.x + acc[i][1] * adv.y +
               acc[i][2] * adv.z + acc[i][3] * adv.w;
#pragma unroll
    for (int m = 1; m < 32; m <<= 1) {
      ps += __shfl_xor(ps, m);
      pd += __shfl_xor(pd, m);
    }
    int row = row0 + (ty << 2) + i;
    if (tx == 0 && row < N_NODES) { As[row] = ps; Ad[row] = pd; }
    if (row < N_NODES) {
      ushort4 hv{f2bf(acc[i][0]), f2bf(acc[i][1]),
                 f2bf(acc[i][2]), f2bf(acc[i][3])};
      *(ushort4*)&Hb[row * 128 + (tx << 2)] = hv;
    }
  }
}

// ------------------------------------- attention softmax + aggregation (CSR)
// one wave per dst node; 4 edges per step (quarter-waves), bf16x8 per lane.
__global__ __launch_bounds__(256) void k_agg(const ushort_t* __restrict__ Hb,
                                             const float* __restrict__ a_s,
                                             const float* __restrict__ a_d,
                                             const int* __restrict__ indptr,
                                             const int* __restrict__ csr_src,
                                             const float* __restrict__ bias,
                                             float* __restrict__ OUT) {
  int n = blockIdx.x * 4 + (threadIdx.x >> 6);
  if (n >= N_NODES) return;
  const int lane = threadIdx.x & 63;
  const int start = indptr[n];
  const int deg = indptr[n + 1] - start;   // >= 1 (self-loop)
  const float adn = a_d[n];

  // ---- softmax stats; lane caches its first edge in registers ----
  int   s0 = csr_src[start + ((lane < deg) ? lane : 0)];
  float e0 = -1e30f;
  if (lane < deg) {
    float e = a_s[s0] + adn;
    e0 = (e > 0.f) ? e : 0.2f * e;
  }
  float lmax = e0;
  for (int j = lane + 64; j < deg; j += 64) {
    float e = a_s[csr_src[start + j]] + adn;
    e = (e > 0.f) ? e : 0.2f * e;
    lmax = fmaxf(lmax, e);
  }
#pragma unroll
  for (int m = 1; m < 64; m <<= 1) lmax = fmaxf(lmax, __shfl_xor(lmax, m));

  float ex0 = (lane < deg) ? __expf(e0 - lmax) : 0.f;
  float lsum = ex0;
  for (int j = lane + 64; j < deg; j += 64) {
    float e = a_s[csr_src[start + j]] + adn;
    e = (e > 0.f) ? e : 0.2f * e;
    lsum += __expf(e - lmax);
  }
#pragma unroll
  for (int m = 1; m < 64; m <<= 1) lsum += __shfl_xor(lsum, m);
  const float inv = 1.0f / lsum;

  // ---- aggregation: 4 edges/step, 16 lanes x 8 bf16 channels per edge ----
  const int q = lane >> 4;            // my edge slot within a step
  const int ch = (lane & 15) << 3;    // my 8 channels
  float acc8[8] = {0.f, 0.f, 0.f, 0.f, 0.f, 0.f, 0.f, 0.f};

#define FMA8(W4, A)                                                         \
  {                                                                         \
    float a_ = (A);                                                         \
    acc8[0] += a_ * __uint_as_float((W4).x << 16);                          \
    acc8[1] += a_ * __uint_as_float((W4).x & 0xFFFF0000u);                  \
    acc8[2] += a_ * __uint_as_float((W4).y << 16);                          \
    acc8[3] += a_ * __uint_as_float((W4).y & 0xFFFF0000u);                  \
    acc8[4] += a_ * __uint_as_float((W4).z << 16);                          \
    acc8[5] += a_ * __uint_as_float((W4).z & 0xFFFF0000u);                  \
    acc8[6] += a_ * __uint_as_float((W4).w << 16);                          \
    acc8[7] += a_ * __uint_as_float((W4).w & 0xFFFF0000u);                  \
  }

  for (int base = 0; base < deg; base += 64) {
    float myal;
    int mys;
    if (base == 0) {
      myal = ex0 * inv;               // 0 for lane >= deg
      mys = s0;
    } else {                          // deg > 64: essentially never, but correct
      int j = base + lane;
      mys = csr_src[start + ((j < deg) ? j : 0)];
      myal = 0.f;
      if (j < deg) {
        float e = a_s[mys] + adn;
        e = (e > 0.f) ? e : 0.2f * e;
        myal = __expf(e - lmax) * inv;
      }
    }
    const int cnt = min(deg - base, 64);
    const int np = (cnt + 3) >> 2;    // 4-edge steps this chunk
    int p0 = 0;
    for (; p0 + 4 <= np; p0 += 4) {
      float av[4]; int sv[4]; uint4 hv[4];
#pragma unroll
      for (int u = 0; u < 4; ++u) {
        int j2 = ((p0 + u) << 2) + q;   // <= 63
        av[u] = __shfl(myal, j2);       // 0 when j2 >= cnt
        sv[u] = __shfl(mys, j2);        // valid row either way
      }
#pragma unroll
      for (int u = 0; u < 4; ++u)
        hv[u] = *(const uint4*)&Hb[sv[u] * 128 + ch];
#pragma unroll
      for (int u = 0; u < 4; ++u) FMA8(hv[u], av[u]);
    }
    for (; p0 < np; ++p0) {
      int j2 = (p0 << 2) + q;
      float a = __shfl(myal, j2);
      int s = __shfl(mys, j2);
      uint4 hv = *(const uint4*)&Hb[s * 128 + ch];
      FMA8(hv, a);
    }
  }
#undef FMA8

  // combine the 4 quarter-waves, bias + relu, write
#pragma unroll
  for (int c = 0; c < 8; ++c) {
    acc8[c] += __shfl_xor(acc8[c], 16);
    acc8[c] += __shfl_xor(acc8[c], 32);
  }
  if (q == 0) {
    float4 b0 = *(const float4*)&bias[ch];
    float4 b1 = *(const float4*)&bias[ch + 4];
    float4 o0, o1;
    o0.x = fmaxf(acc8[0] + b0.x, 0.f); o0.y = fmaxf(acc8[1] + b0.y, 0.f);
    o0.z = fmaxf(acc8[2] + b0.z, 0.f); o0.w = fmaxf(acc8[3] + b0.w, 0.f);
    o1.x = fmaxf(acc8[4] + b1.x, 0.f); o1.y = fmaxf(acc8[5] + b1.y, 0.f);
    o1.z = fmaxf(acc8[6] + b1.z, 0.f); o1.w = fmaxf(acc8[7] + b1.w, 0.f);
    *(float4*)&OUT[n * 128 + ch] = o0;
    *(float4*)&OUT[n * 128 + ch + 4] = o1;
  }
}

// ---------------------------------------------- head (128->8, tanh), no atomics
__global__ __launch_bounds__(256) void k_head(const float* __restrict__ H,
                                              const float* __restrict__ Wl,
                                              const float* __restrict__ bl,
                                              float* __restrict__ h8) {
  __shared__ float Wls[8][128];
  int t = threadIdx.x;
#pragma unroll
  for (int i = 0; i < 4; ++i) {
    int idx = t + i * 256;
    Wls[idx >> 7][idx & 127] = Wl[idx];
  }
  __syncthreads();

  int n = blockIdx.x * 4 + (t >> 6);
  if (n >= N_NODES) return;
  int lane = t & 63;
  float2 hv = *(const float2*)&H[n * 128 + 2 * lane];
  float mine = 0.f;
#pragma unroll
  for (int a = 0; a < 8; ++a) {
    float2 wv = *(const float2*)&Wls[a][2 * lane];
    float v = hv.x * wv.x + hv.y * wv.y;
#pragma unroll
    for (int m = 1; m < 64; m <<= 1) v += __shfl_xor(v, m);
    if (lane == a) mine = v;
  }
  if (lane < 8) h8[n * 8 + lane] = tanhf(mine + bl[lane]);
}

// ------------------------------------ mean pool: one block per graph, no atomics
__global__ __launch_bounds__(256) void k_pool(const float* __restrict__ h8,
                                              const int* __restrict__ batch,
                                              float* __restrict__ out) {
  int g = blockIdx.x;
  __shared__ int bounds[2];
  if (threadIdx.x < 2) {
    int target = g + threadIdx.x;
    int lo = 0, hi = N_NODES;
    while (lo < hi) {
      int mid = (lo + hi) >> 1;
      if (batch[mid] < target) lo = mid + 1; else hi = mid;
    }
    bounds[threadIdx.x] = lo;
  }
  __syncthreads();
  int lo = bounds[0], hi = bounds[1];
  int ch = threadIdx.x & 7;
  float acc = 0.f;
  for (int n = lo + (threadIdx.x >> 3); n < hi; n += 32)
    acc += h8[n * 8 + ch];

  __shared__ float red[256];
  red[threadIdx.x] = acc;
  __syncthreads();
  for (int off = 128; off >= 8; off >>= 1) {
    if (threadIdx.x < off) red[threadIdx.x] += red[threadIdx.x + off];
    __syncthreads();
  }
  if (threadIdx.x < 8)
    out[g * 8 + threadIdx.x] = red[threadIdx.x] / fmaxf((float)(hi - lo), 1.0f);
}

// ---------------------------------------------------------------- launcher
extern "C" void kernel_launch(void* const* d_in, const int* in_sizes, int n_in,
                              void* d_out, int out_size, void* d_ws, size_t ws_size,
                              hipStream_t stream) {
  const float* x   = (const float*)d_in[0];
  const int*   ei  = (const int*)d_in[1];
  const int*   bat = (const int*)d_in[2];
  const float* Wm[3]  = {(const float*)d_in[3],  (const float*)d_in[7],  (const float*)d_in[11]};
  const float* asv[3] = {(const float*)d_in[4],  (const float*)d_in[8],  (const float*)d_in[12]};
  const float* adv[3] = {(const float*)d_in[5],  (const float*)d_in[9],  (const float*)d_in[13]};
  const float* bv[3]  = {(const float*)d_in[6],  (const float*)d_in[10], (const float*)d_in[14]};
  const float* Wl  = (const float*)d_in[15];
  const float* bl  = (const float*)d_in[16];
  float* out = (float*)d_out;

  char* w = (char*)d_ws;
  ushort_t* Hb = (ushort_t*)(w + 0);       // 25,600,000 B (bf16 H)
  float* hB    = (float*)(w + 51200000);   // 51,200,000 B (f32 layer out)
  float* a_s   = (float*)(w + 102400000);  // 400,000 B
  float* a_d   = (float*)(w + 102800000);  // 400,000 B
  int*   deg   = (int*)  (w + 103200000);  // 400,000 B
  int*   indptr= (int*)  (w + 103600000);  // 400,128 B
  int*   poscur= (int*)  (w + 104000128);  // 400,000 B
  int*   bsum  = (int*)  (w + 104400128);  // 512 B
  int*   boff  = (int*)  (w + 104400640);  // 512 B
  int*   csr   = (int*)  (w + 104401152);  // 6,800,000 B
  float* h8    = (float*)(w + 0);          // reuse: Hb free after layer-3 agg

  hipMemsetAsync(deg, 0, N_NODES * sizeof(int), stream);

  k_hist   <<<831, 256, 0, stream>>>(ei, deg);
  k_scan1  <<<98, 1024, 0, stream>>>(deg, indptr, bsum);
  k_scan2  <<<1, 64, 0, stream>>>(bsum, boff, indptr, 98);
  k_scan3  <<<98, 1024, 0, stream>>>(indptr, boff, poscur);
  k_scatter<<<831, 256, 0, stream>>>(ei, poscur, csr);

  const float* in = x;
  for (int l = 0; l < 3; ++l) {
    k_gemm<<<(N_NODES + 63) / 64, 512, 0, stream>>>(in, Wm[l], asv[l], adv[l],
                                                    Hb, a_s, a_d);
    k_agg <<<N_NODES / 4, 256, 0, stream>>>(Hb, a_s, a_d, indptr, csr, bv[l], hB);
    in = hB;
  }

  k_head<<<N_NODES / 4, 256, 0, stream>>>(hB, Wl, bl, h8);
  k_pool<<<NGRAPH, 256, 0, stream>>>(h8, bat, out);
}

// Round 6
// 467.077 us; speedup vs baseline: 3.3854x; 1.6486x over previous
//
#include <hip/hip_runtime.h>

#define N_NODES 100000
#define N_EDGES 1600000
#define E_TOT   1700000
#define HID     128
#define NGRAPH  256

typedef unsigned short ushort_t;
typedef unsigned int uint_t;
typedef __attribute__((ext_vector_type(8))) short bf16x8;
typedef __attribute__((ext_vector_type(4))) float f32x4;

__device__ inline ushort_t f2bf(float f) {   // RNE pack
  uint_t u = __float_as_uint(f);
  return (ushort_t)((u + 0x7FFFu + ((u >> 16) & 1u)) >> 16);
}

// ---------------------------------------------------------------- CSR build
// hist also records each edge's arrival rank -> scatter needs no atomics
__global__ __launch_bounds__(256) void k_hist(const int* __restrict__ ei,
                                              int* __restrict__ deg,
                                              int* __restrict__ rank) {
  const int nth = gridDim.x * 256;
  const int tid = blockIdx.x * 256 + threadIdx.x;
  int d[8], r[8];
#pragma unroll
  for (int u = 0; u < 8; ++u) {
    int e = tid + u * nth;
    d[u] = (e < E_TOT) ? ((e < N_EDGES) ? ei[N_EDGES + e] : (e - N_EDGES)) : -1;
  }
#pragma unroll
  for (int u = 0; u < 8; ++u)
    if (d[u] >= 0) r[u] = atomicAdd(&deg[d[u]], 1);
#pragma unroll
  for (int u = 0; u < 8; ++u)
    if (d[u] >= 0) rank[tid + u * nth] = r[u];
}

__global__ __launch_bounds__(1024) void k_scan1(const int* __restrict__ deg,
                                                int* __restrict__ indptr,
                                                int* __restrict__ bsum) {
  __shared__ int sh[1024];
  int t = threadIdx.x;
  int i = blockIdx.x * 1024 + t;
  int v = (i < N_NODES) ? deg[i] : 0;
  sh[t] = v;
  __syncthreads();
  for (int off = 1; off < 1024; off <<= 1) {
    int x = (t >= off) ? sh[t - off] : 0;
    __syncthreads();
    sh[t] += x;
    __syncthreads();
  }
  if (i < N_NODES) indptr[i] = sh[t] - v;  // exclusive
  if (t == 1023) bsum[blockIdx.x] = sh[1023];
}

__global__ void k_scan2(const int* __restrict__ bsum, int* __restrict__ boff,
                        int* __restrict__ indptr, int nb) {
  if (threadIdx.x == 0 && blockIdx.x == 0) {
    int run = 0;
    for (int i = 0; i < nb; ++i) { boff[i] = run; run += bsum[i]; }
    indptr[N_NODES] = run;
  }
}

__global__ __launch_bounds__(1024) void k_scan3(int* __restrict__ indptr,
                                                const int* __restrict__ boff) {
  int i = blockIdx.x * 1024 + threadIdx.x;
  if (i < N_NODES) indptr[i] += boff[blockIdx.x];
}

__global__ __launch_bounds__(256) void k_scatter(const int* __restrict__ ei,
                                                 const int* __restrict__ indptr,
                                                 const int* __restrict__ rank,
                                                 int* __restrict__ csr_src) {
  const int nth = gridDim.x * 256;
  const int tid = blockIdx.x * 256 + threadIdx.x;
  int src[8], dst[8], rk[8];
#pragma unroll
  for (int u = 0; u < 8; ++u) {
    int e = tid + u * nth;
    if (e < E_TOT) {
      if (e < N_EDGES) { src[u] = ei[e]; dst[u] = ei[N_EDGES + e]; }
      else             { src[u] = e - N_EDGES; dst[u] = src[u]; }
      rk[u] = rank[e];
    } else { src[u] = -1; dst[u] = 0; rk[u] = 0; }
  }
  int p[8];
#pragma unroll
  for (int u = 0; u < 8; ++u)
    if (src[u] >= 0) p[u] = indptr[dst[u]] + rk[u];
#pragma unroll
  for (int u = 0; u < 8; ++u)
    if (src[u] >= 0) csr_src[p[u]] = src[u];
}

// -------------------------------- MFMA GEMM h = X @ W^T (+ a_s/a_d), bf16 out
// block 256 thr (4 waves); tile 64 rows x 128 cols; mfma_f32_16x16x32_bf16.
// LDS: W bf16 [128][128] + X-tile bf16 [64][128], both XOR-swizzled
// (byte ^= (row&7)<<4) so ds_read_b128 fragments are ~conflict-free.
template <bool IN_F32>
__global__ __launch_bounds__(256) void k_gemm(const void* __restrict__ Xin,
                                              const float* __restrict__ W,
                                              const float* __restrict__ att_s,
                                              const float* __restrict__ att_d,
                                              ushort_t* __restrict__ Hb,
                                              float* __restrict__ As,
                                              float* __restrict__ Ad) {
  __shared__ ushort_t Wl[128 * 128];  // 32 KB
  __shared__ ushort_t Xl[64 * 128];   // 16 KB (reused as epilogue stage)
  const int t = threadIdx.x;
  const int row0 = blockIdx.x * 64;

  // stage W (f32 -> bf16, swizzled)
#pragma unroll
  for (int i = 0; i < 16; ++i) {
    int idx = (t + i * 256) << 2;     // float index
    int o = idx >> 7, c = idx & 127;
    float4 w = *(const float4*)&W[idx];
    ushort4 wb{f2bf(w.x), f2bf(w.y), f2bf(w.z), f2bf(w.w)};
    *(ushort4*)((char*)Wl + o * 256 + ((c * 2) ^ ((o & 7) << 4))) = wb;
  }
  // stage X tile
  if (IN_F32) {
    const float* X = (const float*)Xin;
#pragma unroll
    for (int i = 0; i < 8; ++i) {
      int idx = (t + i * 256) << 2;
      int r = idx >> 7, c = idx & 127;
      int row = row0 + r;
      float4 xv = (row < N_NODES) ? *(const float4*)&X[row * 128 + c]
                                  : float4{0.f, 0.f, 0.f, 0.f};
      ushort4 xb{f2bf(xv.x), f2bf(xv.y), f2bf(xv.z), f2bf(xv.w)};
      *(ushort4*)((char*)Xl + r * 256 + ((c * 2) ^ ((r & 7) << 4))) = xb;
    }
  } else {
    const ushort_t* X = (const ushort_t*)Xin;
#pragma unroll
    for (int i = 0; i < 4; ++i) {
      int idx = (t + i * 256) << 3;   // ushort index, 8 per iter
      int r = idx >> 7, c = idx & 127;
      int row = row0 + r;
      uint4 xv = (row < N_NODES) ? *(const uint4*)&X[row * 128 + c]
                                 : uint4{0u, 0u, 0u, 0u};
      *(uint4*)((char*)Xl + r * 256 + ((c * 2) ^ ((r & 7) << 4))) = xv;
    }
  }
  __syncthreads();

  const int wv = t >> 6;         // wave id: rows wv*16 .. +15
  const int lane = t & 63;
  const int lr = lane & 15;      // row (A) / col (B,D) within tile
  const int lg = lane >> 4;      // k-group
  f32x4 acc[8] = {};

#pragma unroll
  for (int ks = 0; ks < 4; ++ks) {
    const int kbyte = ks * 64 + lg * 16;
    const int arow = wv * 16 + lr;
    bf16x8 afrag = *(const bf16x8*)((char*)Xl + arow * 256 +
                                    (kbyte ^ ((arow & 7) << 4)));
#pragma unroll
    for (int ot = 0; ot < 8; ++ot) {
      const int orow = ot * 16 + lr;
      bf16x8 bfrag = *(const bf16x8*)((char*)Wl + orow * 256 +
                                      (kbyte ^ ((orow & 7) << 4)));
      acc[ot] = __builtin_amdgcn_mfma_f32_16x16x32_bf16(afrag, bfrag, acc[ot],
                                                        0, 0, 0);
    }
  }

  // fused a_s/a_d epilogue: lane holds rows wv*16+lg*4+j, cols ot*16+lr
  float ps[4] = {0.f, 0.f, 0.f, 0.f}, pd[4] = {0.f, 0.f, 0.f, 0.f};
#pragma unroll
  for (int ot = 0; ot < 8; ++ot) {
    float sa = att_s[ot * 16 + lr], sd = att_d[ot * 16 + lr];
#pragma unroll
    for (int j = 0; j < 4; ++j) {
      ps[j] += acc[ot][j] * sa;
      pd[j] += acc[ot][j] * sd;
    }
  }
#pragma unroll
  for (int m = 1; m < 16; m <<= 1) {
#pragma unroll
    for (int j = 0; j < 4; ++j) {
      ps[j] += __shfl_xor(ps[j], m);
      pd[j] += __shfl_xor(pd[j], m);
    }
  }
  if (lr == 0) {
#pragma unroll
    for (int j = 0; j < 4; ++j) {
      int row = row0 + wv * 16 + lg * 4 + j;
      if (row < N_NODES) { As[row] = ps[j]; Ad[row] = pd[j]; }
    }
  }

  // stage D tile (bf16, swizzled) in Xl, then coalesced write
  __syncthreads();
#pragma unroll
  for (int ot = 0; ot < 8; ++ot)
#pragma unroll
    for (int j = 0; j < 4; ++j) {
      int r = wv * 16 + lg * 4 + j;
      int cbyte = (ot * 16 + lr) * 2;
      *(ushort_t*)((char*)Xl + r * 256 + (cbyte ^ ((r & 7) << 4))) =
          f2bf(acc[ot][j]);
    }
  __syncthreads();
#pragma unroll
  for (int i = 0; i < 4; ++i) {
    int idx = t + i * 256;
    int r = idx >> 4, u = idx & 15;
    int row = row0 + r;
    if (row < N_NODES)
      *(uint4*)&Hb[row * 128 + u * 8] =
          *(const uint4*)((char*)Xl + r * 256 + ((u * 16) ^ ((r & 7) << 4)));
  }
}

// ------------------------------------- attention softmax + aggregation (CSR)
// one wave per dst node; 4 edges/step (quarter-waves), bf16x8 per lane.
__global__ __launch_bounds__(256) void k_agg(const ushort_t* __restrict__ Hb,
                                             const float* __restrict__ a_s,
                                             const float* __restrict__ a_d,
                                             const int* __restrict__ indptr,
                                             const int* __restrict__ csr_src,
                                             const float* __restrict__ bias,
                                             ushort_t* __restrict__ OUTb) {
  int n = blockIdx.x * 4 + (threadIdx.x >> 6);
  if (n >= N_NODES) return;
  const int lane = threadIdx.x & 63;
  const int start = indptr[n];
  const int deg = indptr[n + 1] - start;   // >= 1 (self-loop)
  const float adn = a_d[n];

  int   s0 = csr_src[start + ((lane < deg) ? lane : 0)];
  float e0 = -1e30f;
  if (lane < deg) {
    float e = a_s[s0] + adn;
    e0 = (e > 0.f) ? e : 0.2f * e;
  }
  float lmax = e0;
  for (int j = lane + 64; j < deg; j += 64) {
    float e = a_s[csr_src[start + j]] + adn;
    e = (e > 0.f) ? e : 0.2f * e;
    lmax = fmaxf(lmax, e);
  }
#pragma unroll
  for (int m = 1; m < 64; m <<= 1) lmax = fmaxf(lmax, __shfl_xor(lmax, m));

  float ex0 = (lane < deg) ? __expf(e0 - lmax) : 0.f;
  float lsum = ex0;
  for (int j = lane + 64; j < deg; j += 64) {
    float e = a_s[csr_src[start + j]] + adn;
    e = (e > 0.f) ? e : 0.2f * e;
    lsum += __expf(e - lmax);
  }
#pragma unroll
  for (int m = 1; m < 64; m <<= 1) lsum += __shfl_xor(lsum, m);
  const float inv = 1.0f / lsum;

  const int q = lane >> 4;            // my edge slot within a step
  const int ch = (lane & 15) << 3;    // my 8 channels
  float acc8[8] = {0.f, 0.f, 0.f, 0.f, 0.f, 0.f, 0.f, 0.f};

#define FMA8(W4, A)                                                         \
  {                                                                         \
    float a_ = (A);                                                         \
    acc8[0] += a_ * __uint_as_float((W4).x << 16);                          \
    acc8[1] += a_ * __uint_as_float((W4).x & 0xFFFF0000u);                  \
    acc8[2] += a_ * __uint_as_float((W4).y << 16);                          \
    acc8[3] += a_ * __uint_as_float((W4).y & 0xFFFF0000u);                  \
    acc8[4] += a_ * __uint_as_float((W4).z << 16);                          \
    acc8[5] += a_ * __uint_as_float((W4).z & 0xFFFF0000u);                  \
    acc8[6] += a_ * __uint_as_float((W4).w << 16);                          \
    acc8[7] += a_ * __uint_as_float((W4).w & 0xFFFF0000u);                  \
  }

  for (int base = 0; base < deg; base += 64) {
    float myal;
    int mys;
    if (base == 0) {
      myal = ex0 * inv;
      mys = s0;
    } else {
      int j = base + lane;
      mys = csr_src[start + ((j < deg) ? j : 0)];
      myal = 0.f;
      if (j < deg) {
        float e = a_s[mys] + adn;
        e = (e > 0.f) ? e : 0.2f * e;
        myal = __expf(e - lmax) * inv;
      }
    }
    const int cnt = min(deg - base, 64);
    const int np = (cnt + 3) >> 2;
    int p0 = 0;
    for (; p0 + 4 <= np; p0 += 4) {
      float av[4]; int sv[4]; uint4 hv[4];
#pragma unroll
      for (int u = 0; u < 4; ++u) {
        int j2 = ((p0 + u) << 2) + q;
        av[u] = __shfl(myal, j2);
        sv[u] = __shfl(mys, j2);
      }
#pragma unroll
      for (int u = 0; u < 4; ++u)
        hv[u] = *(const uint4*)&Hb[sv[u] * 128 + ch];
#pragma unroll
      for (int u = 0; u < 4; ++u) FMA8(hv[u], av[u]);
    }
    for (; p0 < np; ++p0) {
      int j2 = (p0 << 2) + q;
      float a = __shfl(myal, j2);
      int s = __shfl(mys, j2);
      uint4 hv = *(const uint4*)&Hb[s * 128 + ch];
      FMA8(hv, a);
    }
  }
#undef FMA8

#pragma unroll
  for (int c = 0; c < 8; ++c) {
    acc8[c] += __shfl_xor(acc8[c], 16);
    acc8[c] += __shfl_xor(acc8[c], 32);
  }
  if (q == 0) {
    float4 b0 = *(const float4*)&bias[ch];
    float4 b1 = *(const float4*)&bias[ch + 4];
    ushort4 lo{f2bf(fmaxf(acc8[0] + b0.x, 0.f)),
               f2bf(fmaxf(acc8[1] + b0.y, 0.f)),
               f2bf(fmaxf(acc8[2] + b0.z, 0.f)),
               f2bf(fmaxf(acc8[3] + b0.w, 0.f))};
    ushort4 hi{f2bf(fmaxf(acc8[4] + b1.x, 0.f)),
               f2bf(fmaxf(acc8[5] + b1.y, 0.f)),
               f2bf(fmaxf(acc8[6] + b1.z, 0.f)),
               f2bf(fmaxf(acc8[7] + b1.w, 0.f))};
    *(ushort4*)&OUTb[n * 128 + ch] = lo;
    *(ushort4*)&OUTb[n * 128 + ch + 4] = hi;
  }
}

// ---------------------------------------------- head (128->8, tanh), bf16 in
__global__ __launch_bounds__(256) void k_head(const ushort_t* __restrict__ Hb,
                                              const float* __restrict__ Wl,
                                              const float* __restrict__ bl,
                                              float* __restrict__ h8) {
  __shared__ float Wls[8][128];
  int t = threadIdx.x;
#pragma unroll
  for (int i = 0; i < 4; ++i) {
    int idx = t + i * 256;
    Wls[idx >> 7][idx & 127] = Wl[idx];
  }
  __syncthreads();

  int n = blockIdx.x * 4 + (t >> 6);
  if (n >= N_NODES) return;
  int lane = t & 63;
  uint_t hv = *(const uint_t*)&Hb[n * 128 + 2 * lane];
  float hx = __uint_as_float((hv & 0xFFFFu) << 16);
  float hy = __uint_as_float(hv & 0xFFFF0000u);
  float mine = 0.f;
#pragma unroll
  for (int a = 0; a < 8; ++a) {
    float2 wv = *(const float2*)&Wls[a][2 * lane];
    float v = hx * wv.x + hy * wv.y;
#pragma unroll
    for (int m = 1; m < 64; m <<= 1) v += __shfl_xor(v, m);
    if (lane == a) mine = v;
  }
  if (lane < 8) h8[n * 8 + lane] = tanhf(mine + bl[lane]);
}

// ------------------------------------ mean pool: one block per graph
__global__ __launch_bounds__(256) void k_pool(const float* __restrict__ h8,
                                              const int* __restrict__ batch,
                                              float* __restrict__ out) {
  int g = blockIdx.x;
  __shared__ int bounds[2];
  if (threadIdx.x < 2) {
    int target = g + threadIdx.x;
    int lo = 0, hi = N_NODES;
    while (lo < hi) {
      int mid = (lo + hi) >> 1;
      if (batch[mid] < target) lo = mid + 1; else hi = mid;
    }
    bounds[threadIdx.x] = lo;
  }
  __syncthreads();
  int lo = bounds[0], hi = bounds[1];
  int ch = threadIdx.x & 7;
  float acc = 0.f;
  for (int n = lo + (threadIdx.x >> 3); n < hi; n += 32)
    acc += h8[n * 8 + ch];

  __shared__ float red[256];
  red[threadIdx.x] = acc;
  __syncthreads();
  for (int off = 128; off >= 8; off >>= 1) {
    if (threadIdx.x < off) red[threadIdx.x] += red[threadIdx.x + off];
    __syncthreads();
  }
  if (threadIdx.x < 8)
    out[g * 8 + threadIdx.x] = red[threadIdx.x] / fmaxf((float)(hi - lo), 1.0f);
}

// ---------------------------------------------------------------- launcher
extern "C" void kernel_launch(void* const* d_in, const int* in_sizes, int n_in,
                              void* d_out, int out_size, void* d_ws, size_t ws_size,
                              hipStream_t stream) {
  const float* x   = (const float*)d_in[0];
  const int*   ei  = (const int*)d_in[1];
  const int*   bat = (const int*)d_in[2];
  const float* Wm[3]  = {(const float*)d_in[3],  (const float*)d_in[7],  (const float*)d_in[11]};
  const float* asv[3] = {(const float*)d_in[4],  (const float*)d_in[8],  (const float*)d_in[12]};
  const float* adv[3] = {(const float*)d_in[5],  (const float*)d_in[9],  (const float*)d_in[13]};
  const float* bv[3]  = {(const float*)d_in[6],  (const float*)d_in[10], (const float*)d_in[14]};
  const float* Wl  = (const float*)d_in[15];
  const float* bl  = (const float*)d_in[16];
  float* out = (float*)d_out;

  char* w = (char*)d_ws;
  ushort_t* Hb   = (ushort_t*)(w + 0);         // 25,600,000 B (gemm out, bf16)
  ushort_t* hB2  = (ushort_t*)(w + 25600000);  // 25,600,000 B (agg out, bf16)
  float* a_s     = (float*)(w + 51200000);     // 400,000 B
  float* a_d     = (float*)(w + 51600000);     // 400,000 B
  int*   deg     = (int*)  (w + 52000000);     // 400,000 B
  int*   indptr  = (int*)  (w + 52400000);     // 400,128 B
  int*   bsum    = (int*)  (w + 52800128);     // 512 B
  int*   boff    = (int*)  (w + 52800640);     // 512 B
  int*   csr     = (int*)  (w + 52801152);     // 6,800,000 B
  int*   rankb   = (int*)  (w + 59601152);     // 6,800,000 B
  float* h8      = (float*)(w + 0);            // reuse Hb after layer-3 agg

  hipMemsetAsync(deg, 0, N_NODES * sizeof(int), stream);

  k_hist   <<<831, 256, 0, stream>>>(ei, deg, rankb);
  k_scan1  <<<98, 1024, 0, stream>>>(deg, indptr, bsum);
  k_scan2  <<<1, 64, 0, stream>>>(bsum, boff, indptr, 98);
  k_scan3  <<<98, 1024, 0, stream>>>(indptr, boff);
  k_scatter<<<831, 256, 0, stream>>>(ei, indptr, rankb, csr);

  const int gblk = (N_NODES + 63) / 64;
  k_gemm<true><<<gblk, 256, 0, stream>>>(x, Wm[0], asv[0], adv[0], Hb, a_s, a_d);
  k_agg<<<N_NODES / 4, 256, 0, stream>>>(Hb, a_s, a_d, indptr, csr, bv[0], hB2);
  for (int l = 1; l < 3; ++l) {
    k_gemm<false><<<gblk, 256, 0, stream>>>(hB2, Wm[l], asv[l], adv[l], Hb, a_s, a_d);
    k_agg<<<N_NODES / 4, 256, 0, stream>>>(Hb, a_s, a_d, indptr, csr, bv[l], hB2);
  }

  k_head<<<N_NODES / 4, 256, 0, stream>>>(hB2, Wl, bl, h8);
  k_pool<<<NGRAPH, 256, 0, stream>>>(h8, bat, out);
}